// Round 8
// baseline (111.560 us; speedup 1.0000x reference)
//
#include <hip/hip_runtime.h>

#define KEPS  1e-16f
#define LOG2E 1.44269504088896340736f

// ---- d_ws float layout (2178 floats) ----
// [0..99]      tsc : 1/(nmax-nmin+eps)              [c][f]
// [100..199]   tbi : -nmin*tsc                      [c][f]
// [200..999]   tew : tail_enc_w * -log2e            [c][i][f]
// [1000..1079] teb : tail_enc_b * -log2e            [c][i]
// [1080..1879] tdw : tail_dec_w * -log2e            [c][f][i]
// [1880..1979] tdb : tail_dec_b * -log2e            [c][f]
// [1980..1989] hsc : head scale                     [c]
// [1990..1999] hbi : -hnmin*hsc                     [c]
// [2000..2079] hewS: head_enc_w * -log2e            [i][c]
// [2080..2087] hebS: head_enc_b * -log2e            [i]
// [2088..2167] hdwS: head_dec_w * -log2e            [c][i]
// [2168..2177] hdbS: head_dec_b * -log2e            [c]

__global__ void kitsune_prep(
    const float* __restrict__ tew, const float* __restrict__ teb,
    const float* __restrict__ tdw, const float* __restrict__ tdb,
    const float* __restrict__ tnmin, const float* __restrict__ tnmax,
    const float* __restrict__ hew, const float* __restrict__ heb,
    const float* __restrict__ hdw, const float* __restrict__ hdb,
    const float* __restrict__ hnmin, const float* __restrict__ hnmax,
    float* __restrict__ ws)
{
    const int i = threadIdx.x;  // one block of 256
    for (int k = i; k < 100; k += 256) {
        float s = 1.0f / (tnmax[k] - tnmin[k] + KEPS);
        ws[k]        = s;
        ws[100 + k]  = -tnmin[k] * s;
        ws[1880 + k] = tdb[k] * -LOG2E;
    }
    for (int k = i; k < 800; k += 256) {
        ws[200 + k]  = tew[k] * -LOG2E;
        ws[1080 + k] = tdw[k] * -LOG2E;
    }
    for (int k = i; k < 80; k += 256) {
        ws[1000 + k] = teb[k] * -LOG2E;
        ws[2000 + k] = hew[k] * -LOG2E;   // [i][c]
        ws[2088 + k] = hdw[k] * -LOG2E;   // [c][i]
    }
    if (i < 10) {
        float s = 1.0f / (hnmax[i] - hnmin[i] + KEPS);
        ws[1980 + i] = s;
        ws[1990 + i] = -hnmin[i] * s;
        ws[2168 + i] = hdb[i] * -LOG2E;
    }
    if (i < 8) ws[2080 + i] = heb[i] * -LOG2E;
}

// sigmoid with -log2e pre-folded into the matmul: sig2(a) = 1/(1+2^a)
__device__ __forceinline__ float sig2(float a) {
    return __builtin_amdgcn_rcpf(1.0f + __builtin_amdgcn_exp2f(a));
}

// Block = 640 threads = 10 waves; tile = 128 rows. Wave w = cluster w; each
// lane handles rows (lane) and (lane+64): two independent chains per lane,
// and every scalar weight load is amortized over 2 rows.
__global__ __launch_bounds__(640) void kitsune_main(
    const float* __restrict__ x,    // [B][100]
    const float* __restrict__ ws,   // prepped params
    float* __restrict__ out_xhat,   // [B][10]
    float* __restrict__ out_t,      // [B][10]
    int B)
{
    __shared__ float xs[128 * 102]; // input tile, row stride 102 (<=4-way on b64)
    __shared__ float ts[128 * 11];  // t values (stride 11: conflict-free)
    __shared__ float hs[128 * 9];   // head hidden (post-sigmoid)
    __shared__ float os[128 * 11];  // xhat

    const int tid  = threadIdx.x;
    const int base = (int)blockIdx.x * 128;
    const int rows = min(128, B - base);
    const int n25  = rows * 25;

    // ---- phase 1: stage tile, fully coalesced float4 loads ----
    {
        const float4* gx = reinterpret_cast<const float4*>(x) + (size_t)base * 25;
        #pragma unroll
        for (int n = 0; n < 5; ++n) {
            int idx = tid + n * 640;          // float4 index in [0, 3200)
            if (idx < n25) {
                float4 v = gx[idx];
                int row = idx / 25;
                int q   = idx - row * 25;
                float* d = xs + row * 102 + q * 4;
                *reinterpret_cast<float2*>(d)     = make_float2(v.x, v.y);
                *reinterpret_cast<float2*>(d + 2) = make_float2(v.z, v.w);
            }
        }
    }
    __syncthreads();

    // ---- phase 2: tail AE; wave w = cluster w; lane = rows r, r+64 ----
    {
        const int c  = __builtin_amdgcn_readfirstlane(tid >> 6);  // 0..9
        const int r0 = tid & 63;
        const int r1 = r0 + 64;

        float xnA[10], xnB[10];
        #pragma unroll
        for (int j = 0; j < 5; ++j) {
            float2 a = *reinterpret_cast<const float2*>(xs + r0 * 102 + c * 10 + 2 * j);
            float2 b = *reinterpret_cast<const float2*>(xs + r1 * 102 + c * 10 + 2 * j);
            xnA[2*j] = a.x; xnA[2*j+1] = a.y;
            xnB[2*j] = b.x; xnB[2*j+1] = b.y;
        }
        #pragma unroll
        for (int f = 0; f < 10; ++f) {
            float s  = ws[c * 10 + f];
            float bi = ws[100 + c * 10 + f];
            xnA[f] = fmaf(xnA[f], s, bi);
            xnB[f] = fmaf(xnB[f], s, bi);
        }

        float hA[8], hB[8];
        #pragma unroll
        for (int i = 0; i < 8; ++i) {
            float a0 = ws[1000 + c * 8 + i];
            float aA = a0, aB = a0;
            #pragma unroll
            for (int f = 0; f < 10; ++f) {
                float w = ws[200 + (c * 8 + i) * 10 + f];
                aA = fmaf(w, xnA[f], aA);
                aB = fmaf(w, xnB[f], aB);
            }
            hA[i] = sig2(aA);
            hB[i] = sig2(aB);
        }

        float s0A = 0.0f, s1A = 0.0f, s0B = 0.0f, s1B = 0.0f;
        #pragma unroll
        for (int f = 0; f < 10; ++f) {
            float a0 = ws[1880 + c * 10 + f];
            float aA = a0, aB = a0;
            #pragma unroll
            for (int i = 0; i < 8; ++i) {
                float w = ws[1080 + (c * 10 + f) * 8 + i];
                aA = fmaf(w, hA[i], aA);
                aB = fmaf(w, hB[i], aB);
            }
            float dA = sig2(aA) - xnA[f];
            float dB = sig2(aB) - xnB[f];
            if (f & 1) { s1A = fmaf(dA, dA, s1A); s1B = fmaf(dB, dB, s1B); }
            else       { s0A = fmaf(dA, dA, s0A); s0B = fmaf(dB, dB, s0B); }
        }
        float lA = __fsqrt_rn((s0A + s1A) * 0.1f);
        float lB = __fsqrt_rn((s0B + s1B) * 0.1f);
        float tailA = (lA == 0.0f) ? 0.01f : lA;
        float tailB = (lB == 0.0f) ? 0.01f : lB;
        float hsc = ws[1980 + c], hbi = ws[1990 + c];
        ts[r0 * 11 + c] = fmaf(tailA, hsc, hbi);
        ts[r1 * 11 + c] = fmaf(tailB, hsc, hbi);
    }
    __syncthreads();

    // ---- phase 3a: head encoder; waves 0..7 = unit i; lane = rows r, r+64 ----
    if (tid < 512) {
        const int i  = __builtin_amdgcn_readfirstlane(tid >> 6);  // 0..7
        const int r0 = tid & 63;
        const int r1 = r0 + 64;
        float aA = ws[2080 + i], aB = aA;
        #pragma unroll
        for (int cc = 0; cc < 10; ++cc) {
            float w = ws[2000 + i * 10 + cc];
            aA = fmaf(w, ts[r0 * 11 + cc], aA);
            aB = fmaf(w, ts[r1 * 11 + cc], aB);
        }
        hs[r0 * 9 + i] = sig2(aA);
        hs[r1 * 9 + i] = sig2(aB);
    }
    __syncthreads();

    // ---- phase 3b: head decoder; wave w = output c; lane = rows r, r+64 ----
    {
        const int c  = __builtin_amdgcn_readfirstlane(tid >> 6);  // 0..9
        const int r0 = tid & 63;
        const int r1 = r0 + 64;
        float aA = ws[2168 + c], aB = aA;
        #pragma unroll
        for (int i = 0; i < 8; ++i) {
            float w = ws[2088 + c * 8 + i];
            aA = fmaf(w, hs[r0 * 9 + i], aA);
            aB = fmaf(w, hs[r1 * 9 + i], aB);
        }
        os[r0 * 11 + c] = sig2(aA);
        os[r1 * 11 + c] = sig2(aB);
    }
    __syncthreads();

    // ---- phase 4: coalesced float2 stores; tid*8B is exactly linear ----
    {
        int row = tid / 5, j = tid - row * 5;   // 640 = 128 rows x 5 float2
        if (row < rows) {
            float2 v = make_float2(ts[row * 11 + 2 * j], ts[row * 11 + 2 * j + 1]);
            *reinterpret_cast<float2*>(out_t + (size_t)(base + row) * 10 + 2 * j) = v;
            float2 u = make_float2(os[row * 11 + 2 * j], os[row * 11 + 2 * j + 1]);
            *reinterpret_cast<float2*>(out_xhat + (size_t)(base + row) * 10 + 2 * j) = u;
        }
    }
}

extern "C" void kernel_launch(void* const* d_in, const int* in_sizes, int n_in,
                              void* d_out, int out_size, void* d_ws, size_t ws_size,
                              hipStream_t stream) {
    const float* x          = (const float*)d_in[0];
    const float* tail_enc_w = (const float*)d_in[1];
    const float* tail_enc_b = (const float*)d_in[2];
    const float* tail_dec_w = (const float*)d_in[3];
    const float* tail_dec_b = (const float*)d_in[4];
    const float* tail_nmin  = (const float*)d_in[5];
    const float* tail_nmax  = (const float*)d_in[6];
    const float* head_enc_w = (const float*)d_in[7];
    const float* head_enc_b = (const float*)d_in[8];
    const float* head_dec_w = (const float*)d_in[9];
    const float* head_dec_b = (const float*)d_in[10];
    const float* head_nmin  = (const float*)d_in[11];
    const float* head_nmax  = (const float*)d_in[12];

    const int B = in_sizes[0] / 100;

    float* out_xhat = (float*)d_out;             // [B][10], first in tuple
    float* out_t    = out_xhat + (size_t)B * 10; // [B][10], second in tuple
    float* ws       = (float*)d_ws;

    kitsune_prep<<<1, 256, 0, stream>>>(
        tail_enc_w, tail_enc_b, tail_dec_w, tail_dec_b, tail_nmin, tail_nmax,
        head_enc_w, head_enc_b, head_dec_w, head_dec_b, head_nmin, head_nmax, ws);

    const int grid = (B + 127) / 128;            // 128 rows per block
    kitsune_main<<<grid, 640, 0, stream>>>(x, ws, out_xhat, out_t, B);
}

// Round 9
// 77.088 us; speedup vs baseline: 1.4472x; 1.4472x over previous
//
#include <hip/hip_runtime.h>

#define KEPS  1e-16f
#define LOG2E 1.44269504088896340736f

typedef float v2f __attribute__((ext_vector_type(2)));

// ---- d_ws float layout (2178 floats) ----
// [0..99]      tsc : 1/(nmax-nmin+eps)              [c][f]
// [100..199]   tbi : -nmin*tsc                      [c][f]
// [200..999]   tew : tail_enc_w * -log2e            [c][i][f]
// [1000..1079] teb : tail_enc_b * -log2e            [c][i]
// [1080..1879] tdw : tail_dec_w * -log2e            [c][f][i]
// [1880..1979] tdb : tail_dec_b * -log2e            [c][f]
// [1980..1989] hsc : head scale                     [c]
// [1990..1999] hbi : -hnmin*hsc                     [c]
// [2000..2079] hewS: head_enc_w * -log2e            [i][c]
// [2080..2087] hebS: head_enc_b * -log2e            [i]
// [2088..2167] hdwS: head_dec_w * -log2e            [c][i]
// [2168..2177] hdbS: head_dec_b * -log2e            [c]

__global__ void kitsune_prep(
    const float* __restrict__ tew, const float* __restrict__ teb,
    const float* __restrict__ tdw, const float* __restrict__ tdb,
    const float* __restrict__ tnmin, const float* __restrict__ tnmax,
    const float* __restrict__ hew, const float* __restrict__ heb,
    const float* __restrict__ hdw, const float* __restrict__ hdb,
    const float* __restrict__ hnmin, const float* __restrict__ hnmax,
    float* __restrict__ ws)
{
    const int i = threadIdx.x;  // one block of 256
    for (int k = i; k < 100; k += 256) {
        float s = 1.0f / (tnmax[k] - tnmin[k] + KEPS);
        ws[k]        = s;
        ws[100 + k]  = -tnmin[k] * s;
        ws[1880 + k] = tdb[k] * -LOG2E;
    }
    for (int k = i; k < 800; k += 256) {
        ws[200 + k]  = tew[k] * -LOG2E;
        ws[1080 + k] = tdw[k] * -LOG2E;
    }
    for (int k = i; k < 80; k += 256) {
        ws[1000 + k] = teb[k] * -LOG2E;
        ws[2000 + k] = hew[k] * -LOG2E;   // [i][c]
        ws[2088 + k] = hdw[k] * -LOG2E;   // [c][i]
    }
    if (i < 10) {
        float s = 1.0f / (hnmax[i] - hnmin[i] + KEPS);
        ws[1980 + i] = s;
        ws[1990 + i] = -hnmin[i] * s;
        ws[2168 + i] = hdb[i] * -LOG2E;
    }
    if (i < 8) ws[2080 + i] = heb[i] * -LOG2E;
}

// sigmoid with -log2e pre-folded into the matmul: sig2(a) = 1/(1+2^a)
__device__ __forceinline__ float sig2(float a) {
    return __builtin_amdgcn_rcpf(1.0f + __builtin_amdgcn_exp2f(a));
}

// Block = 640 threads = 10 waves = 64 rows/tile. Wave w = cluster w, lane =
// row. Inner matmuls packed as v2f over the feature/hidden axis -> the
// compiler emits v_pk_fma_f32 (dual fp32 FMA): ~halves phase-2 VALU issue.
__global__ __launch_bounds__(640) void kitsune_main(
    const float* __restrict__ x,    // [B][100]
    const float* __restrict__ ws,   // prepped params
    float* __restrict__ out_xhat,   // [B][10]
    float* __restrict__ out_t,      // [B][10]
    int B)
{
    __shared__ float xs[64 * 102];  // input tile, row stride 102
    __shared__ float ts[64 * 11];   // t values (stride 11: conflict-free)
    __shared__ float hs[64 * 9];    // head hidden (post-sigmoid)
    __shared__ float os[64 * 11];   // xhat

    const int tid  = threadIdx.x;
    const int base = (int)blockIdx.x * 64;
    const int rows = min(64, B - base);
    const int n25  = rows * 25;

    // ---- phase 1: stage tile, fully coalesced float4 loads ----
    {
        const float4* gx = reinterpret_cast<const float4*>(x) + (size_t)base * 25;
        #pragma unroll
        for (int n = 0; n < 3; ++n) {
            int idx = tid + n * 640;          // float4 index in [0, 1600)
            if (idx < n25) {
                float4 v = gx[idx];
                int row = idx / 25;
                int q   = idx - row * 25;
                float* d = xs + row * 102 + q * 4;
                *reinterpret_cast<float2*>(d)     = make_float2(v.x, v.y);
                *reinterpret_cast<float2*>(d + 2) = make_float2(v.z, v.w);
            }
        }
    }
    __syncthreads();

    // ---- phase 2: tail AE; wave w = cluster w, lane = row; packed math ----
    {
        const int c = __builtin_amdgcn_readfirstlane(tid >> 6);  // 0..9
        const int r = tid & 63;

        // load 5 feature-pairs (8B-aligned: 102r + 10c + 2j all even)
        v2f xp[5];
        #pragma unroll
        for (int j = 0; j < 5; ++j)
            xp[j] = *reinterpret_cast<const v2f*>(xs + r * 102 + c * 10 + 2 * j);

        // normalise: packed fma with wave-uniform scale/bias pairs
        const v2f* sc2 = reinterpret_cast<const v2f*>(ws + c * 10);
        const v2f* bi2 = reinterpret_cast<const v2f*>(ws + 100 + c * 10);
        #pragma unroll
        for (int j = 0; j < 5; ++j)
            xp[j] = __builtin_elementwise_fma(xp[j], sc2[j], bi2[j]);

        // encoder: 5 pk_fma per hidden unit (was 10 scalar fma)
        v2f hv[4];
        #pragma unroll
        for (int i = 0; i < 8; ++i) {
            const v2f* w2 = reinterpret_cast<const v2f*>(ws + 200 + (c * 8 + i) * 10);
            v2f a2 = w2[0] * xp[0];
            #pragma unroll
            for (int j = 1; j < 5; ++j)
                a2 = __builtin_elementwise_fma(w2[j], xp[j], a2);
            hv[i >> 1][i & 1] = sig2(ws[1000 + c * 8 + i] + a2.x + a2.y);
        }

        // decoder + RMSE: 4 pk_fma per output feature (was 8 scalar fma)
        v2f ss2 = {0.0f, 0.0f};
        float dprev = 0.0f;
        #pragma unroll
        for (int f = 0; f < 10; ++f) {
            const v2f* w2 = reinterpret_cast<const v2f*>(ws + 1080 + (c * 10 + f) * 8);
            v2f a2 = w2[0] * hv[0];
            #pragma unroll
            for (int i = 1; i < 4; ++i)
                a2 = __builtin_elementwise_fma(w2[i], hv[i], a2);
            float rec = sig2(ws[1880 + c * 10 + f] + a2.x + a2.y);
            float d   = rec - xp[f >> 1][f & 1];
            if (f & 1) {
                v2f d2 = {dprev, d};
                ss2 = __builtin_elementwise_fma(d2, d2, ss2);
            } else {
                dprev = d;
            }
        }
        float l    = __builtin_amdgcn_sqrtf((ss2.x + ss2.y) * 0.1f);
        float tail = (l == 0.0f) ? 0.01f : l;
        ts[r * 11 + c] = fmaf(tail, ws[1980 + c], ws[1990 + c]);
    }
    __syncthreads();

    // ---- phase 3a: head encoder; waves 0..7 = unit i, lane = row ----
    if (tid < 512) {
        const int i = __builtin_amdgcn_readfirstlane(tid >> 6);  // 0..7
        const int r = tid & 63;
        float a = ws[2080 + i];
        #pragma unroll
        for (int cc = 0; cc < 10; ++cc)
            a = fmaf(ws[2000 + i * 10 + cc], ts[r * 11 + cc], a);
        hs[r * 9 + i] = sig2(a);
    }
    __syncthreads();

    // ---- phase 3b: head decoder; wave w = output c, lane = row ----
    {
        const int c = __builtin_amdgcn_readfirstlane(tid >> 6);  // 0..9
        const int r = tid & 63;
        float a = ws[2168 + c];
        #pragma unroll
        for (int i = 0; i < 8; ++i)
            a = fmaf(ws[2088 + c * 8 + i], hs[r * 9 + i], a);
        os[r * 11 + c] = sig2(a);
    }
    __syncthreads();

    // ---- phase 4: coalesced float2 stores ----
    if (tid < 320) {
        int row = tid / 5, j = tid - row * 5;
        if (row < rows) {
            float2 v = make_float2(ts[row * 11 + 2 * j], ts[row * 11 + 2 * j + 1]);
            *reinterpret_cast<float2*>(out_t + (size_t)(base + row) * 10 + 2 * j) = v;
        }
    } else {
        int q   = tid - 320;
        int row = q / 5, j = q - row * 5;
        if (row < rows) {
            float2 v = make_float2(os[row * 11 + 2 * j], os[row * 11 + 2 * j + 1]);
            *reinterpret_cast<float2*>(out_xhat + (size_t)(base + row) * 10 + 2 * j) = v;
        }
    }
}

extern "C" void kernel_launch(void* const* d_in, const int* in_sizes, int n_in,
                              void* d_out, int out_size, void* d_ws, size_t ws_size,
                              hipStream_t stream) {
    const float* x          = (const float*)d_in[0];
    const float* tail_enc_w = (const float*)d_in[1];
    const float* tail_enc_b = (const float*)d_in[2];
    const float* tail_dec_w = (const float*)d_in[3];
    const float* tail_dec_b = (const float*)d_in[4];
    const float* tail_nmin  = (const float*)d_in[5];
    const float* tail_nmax  = (const float*)d_in[6];
    const float* head_enc_w = (const float*)d_in[7];
    const float* head_enc_b = (const float*)d_in[8];
    const float* head_dec_w = (const float*)d_in[9];
    const float* head_dec_b = (const float*)d_in[10];
    const float* head_nmin  = (const float*)d_in[11];
    const float* head_nmax  = (const float*)d_in[12];

    const int B = in_sizes[0] / 100;

    float* out_xhat = (float*)d_out;             // [B][10], first in tuple
    float* out_t    = out_xhat + (size_t)B * 10; // [B][10], second in tuple
    float* ws       = (float*)d_ws;

    kitsune_prep<<<1, 256, 0, stream>>>(
        tail_enc_w, tail_enc_b, tail_dec_w, tail_dec_b, tail_nmin, tail_nmax,
        head_enc_w, head_enc_b, head_dec_w, head_dec_b, head_nmin, head_nmax, ws);

    const int grid = (B + 63) / 64;              // 64 rows per block
    kitsune_main<<<grid, 640, 0, stream>>>(x, ws, out_xhat, out_t, B);
}

// Round 10
// 72.065 us; speedup vs baseline: 1.5480x; 1.0697x over previous
//
#include <hip/hip_runtime.h>

#define KEPS  1e-16f
#define LOG2E 1.44269504088896340736f

typedef float v2f __attribute__((ext_vector_type(2)));

// ---- d_ws float layout (2178 floats) ----
// [0..99]      tsc : 1/(nmax-nmin+eps)              [c][f]
// [100..199]   tbi : -nmin*tsc                      [c][f]
// [200..999]   tew : tail_enc_w * -log2e            [c][i][f]
// [1000..1079] teb : tail_enc_b * -log2e            [c][i]
// [1080..1879] tdw : tail_dec_w * -log2e            [c][f][i]
// [1880..1979] tdb : tail_dec_b * -log2e            [c][f]
// [1980..1989] hsc : head scale                     [c]
// [1990..1999] hbi : -hnmin*hsc                     [c]
// [2000..2079] hewS: head_enc_w * -log2e            [i][c]
// [2080..2087] hebS: head_enc_b * -log2e            [i]
// [2088..2167] hdwS: head_dec_w * -log2e            [c][i]
// [2168..2177] hdbS: head_dec_b * -log2e            [c]

__global__ void kitsune_prep(
    const float* __restrict__ tew, const float* __restrict__ teb,
    const float* __restrict__ tdw, const float* __restrict__ tdb,
    const float* __restrict__ tnmin, const float* __restrict__ tnmax,
    const float* __restrict__ hew, const float* __restrict__ heb,
    const float* __restrict__ hdw, const float* __restrict__ hdb,
    const float* __restrict__ hnmin, const float* __restrict__ hnmax,
    float* __restrict__ ws)
{
    const int i = threadIdx.x;  // one block of 256
    for (int k = i; k < 100; k += 256) {
        float s = 1.0f / (tnmax[k] - tnmin[k] + KEPS);
        ws[k]        = s;
        ws[100 + k]  = -tnmin[k] * s;
        ws[1880 + k] = tdb[k] * -LOG2E;
    }
    for (int k = i; k < 800; k += 256) {
        ws[200 + k]  = tew[k] * -LOG2E;
        ws[1080 + k] = tdw[k] * -LOG2E;
    }
    for (int k = i; k < 80; k += 256) {
        ws[1000 + k] = teb[k] * -LOG2E;
        ws[2000 + k] = hew[k] * -LOG2E;   // [i][c]
        ws[2088 + k] = hdw[k] * -LOG2E;   // [c][i]
    }
    if (i < 10) {
        float s = 1.0f / (hnmax[i] - hnmin[i] + KEPS);
        ws[1980 + i] = s;
        ws[1990 + i] = -hnmin[i] * s;
        ws[2168 + i] = hdb[i] * -LOG2E;
    }
    if (i < 8) ws[2080 + i] = heb[i] * -LOG2E;
}

// sigmoid with -log2e pre-folded into the matmul: sig2(a) = 1/(1+2^a)
__device__ __forceinline__ float sig2(float a) {
    return __builtin_amdgcn_rcpf(1.0f + __builtin_amdgcn_exp2f(a));
}

// ---- Kernel A: tails. Block = 320 thr = 5 waves = 64 rows, ONE barrier.
// Wave w computes clusters w and w+5 (packed v2f math); writes t straight
// to out_t (one 4B-store inst per cluster). 6 blocks/CU -> 30 waves/CU.
__global__ __launch_bounds__(320) void kitsune_tail(
    const float* __restrict__ x,    // [B][100]
    const float* __restrict__ ws,
    float* __restrict__ out_t,      // [B][10]
    int B)
{
    __shared__ float xs[64 * 102];  // row stride 102

    const int tid  = threadIdx.x;
    const int base = (int)blockIdx.x * 64;
    const int rows = min(64, B - base);
    const int n25  = rows * 25;

    // stage 64 rows, fully coalesced float4 loads
    {
        const float4* gx = reinterpret_cast<const float4*>(x) + (size_t)base * 25;
        #pragma unroll
        for (int n = 0; n < 5; ++n) {
            int idx = tid + n * 320;          // float4 index in [0, 1600)
            if (idx < n25) {
                float4 v = gx[idx];
                int row = idx / 25;
                int q   = idx - row * 25;
                float* d = xs + row * 102 + q * 4;
                *reinterpret_cast<float2*>(d)     = make_float2(v.x, v.y);
                *reinterpret_cast<float2*>(d + 2) = make_float2(v.z, v.w);
            }
        }
    }
    __syncthreads();   // the ONLY barrier

    const int r = tid & 63;

    #pragma unroll
    for (int k = 0; k < 2; ++k) {
        const int c = __builtin_amdgcn_readfirstlane((tid >> 6) + 5 * k); // uniform

        // load 5 feature-pairs (8B-aligned)
        v2f xp[5];
        #pragma unroll
        for (int j = 0; j < 5; ++j)
            xp[j] = *reinterpret_cast<const v2f*>(xs + r * 102 + c * 10 + 2 * j);

        // normalise (packed fma, wave-uniform scale/bias)
        const v2f* sc2 = reinterpret_cast<const v2f*>(ws + c * 10);
        const v2f* bi2 = reinterpret_cast<const v2f*>(ws + 100 + c * 10);
        #pragma unroll
        for (int j = 0; j < 5; ++j)
            xp[j] = __builtin_elementwise_fma(xp[j], sc2[j], bi2[j]);

        // encoder: 5 pk_fma per hidden unit
        v2f hv[4];
        #pragma unroll
        for (int i = 0; i < 8; ++i) {
            const v2f* w2 = reinterpret_cast<const v2f*>(ws + 200 + (c * 8 + i) * 10);
            v2f a2 = w2[0] * xp[0];
            #pragma unroll
            for (int j = 1; j < 5; ++j)
                a2 = __builtin_elementwise_fma(w2[j], xp[j], a2);
            hv[i >> 1][i & 1] = sig2(ws[1000 + c * 8 + i] + a2.x + a2.y);
        }

        // decoder + RMSE: 4 pk_fma per output feature
        v2f ss2 = {0.0f, 0.0f};
        float dprev = 0.0f;
        #pragma unroll
        for (int f = 0; f < 10; ++f) {
            const v2f* w2 = reinterpret_cast<const v2f*>(ws + 1080 + (c * 10 + f) * 8);
            v2f a2 = w2[0] * hv[0];
            #pragma unroll
            for (int i = 1; i < 4; ++i)
                a2 = __builtin_elementwise_fma(w2[i], hv[i], a2);
            float rec = sig2(ws[1880 + c * 10 + f] + a2.x + a2.y);
            float d   = rec - xp[f >> 1][f & 1];
            if (f & 1) {
                v2f d2 = {dprev, d};
                ss2 = __builtin_elementwise_fma(d2, d2, ss2);
            } else {
                dprev = d;
            }
        }
        float l    = __builtin_amdgcn_sqrtf((ss2.x + ss2.y) * 0.1f);
        float tail = (l == 0.0f) ? 0.01f : l;
        float tv   = fmaf(tail, ws[1980 + c], ws[1990 + c]);

        if (r < rows)
            out_t[(size_t)(base + r) * 10 + c] = tv;   // one store inst, 21 MB total
    }
}

// ---- Kernel B: head. Barrier-free, 1 row/thread; reads out_t back (L2-hot),
// packed head math, writes xhat.
__global__ __launch_bounds__(256) void kitsune_head(
    const float* __restrict__ t_in,  // = out_t [B][10]
    const float* __restrict__ ws,
    float* __restrict__ out_xhat,    // [B][10]
    int B)
{
    const int b = blockIdx.x * 256 + threadIdx.x;
    if (b >= B) return;

    v2f tp[5];
    {
        const v2f* tr = reinterpret_cast<const v2f*>(t_in + (size_t)b * 10);
        #pragma unroll
        for (int j = 0; j < 5; ++j) tp[j] = tr[j];
    }

    // encoder: pack over cluster pairs
    v2f hv[4];
    #pragma unroll
    for (int i = 0; i < 8; ++i) {
        const v2f* w2 = reinterpret_cast<const v2f*>(ws + 2000 + i * 10);
        v2f a2 = w2[0] * tp[0];
        #pragma unroll
        for (int j = 1; j < 5; ++j)
            a2 = __builtin_elementwise_fma(w2[j], tp[j], a2);
        hv[i >> 1][i & 1] = sig2(ws[2080 + i] + a2.x + a2.y);
    }

    // decoder: pack over hidden pairs
    float xh[10];
    #pragma unroll
    for (int c = 0; c < 10; ++c) {
        const v2f* w2 = reinterpret_cast<const v2f*>(ws + 2088 + c * 8);
        v2f a2 = w2[0] * hv[0];
        #pragma unroll
        for (int i = 1; i < 4; ++i)
            a2 = __builtin_elementwise_fma(w2[i], hv[i], a2);
        xh[c] = sig2(ws[2168 + c] + a2.x + a2.y);
    }

    float* po = out_xhat + (size_t)b * 10;
    #pragma unroll
    for (int j = 0; j < 5; ++j)
        *reinterpret_cast<float2*>(po + 2 * j) = make_float2(xh[2 * j], xh[2 * j + 1]);
}

extern "C" void kernel_launch(void* const* d_in, const int* in_sizes, int n_in,
                              void* d_out, int out_size, void* d_ws, size_t ws_size,
                              hipStream_t stream) {
    const float* x          = (const float*)d_in[0];
    const float* tail_enc_w = (const float*)d_in[1];
    const float* tail_enc_b = (const float*)d_in[2];
    const float* tail_dec_w = (const float*)d_in[3];
    const float* tail_dec_b = (const float*)d_in[4];
    const float* tail_nmin  = (const float*)d_in[5];
    const float* tail_nmax  = (const float*)d_in[6];
    const float* head_enc_w = (const float*)d_in[7];
    const float* head_enc_b = (const float*)d_in[8];
    const float* head_dec_w = (const float*)d_in[9];
    const float* head_dec_b = (const float*)d_in[10];
    const float* head_nmin  = (const float*)d_in[11];
    const float* head_nmax  = (const float*)d_in[12];

    const int B = in_sizes[0] / 100;

    float* out_xhat = (float*)d_out;             // [B][10], first in tuple
    float* out_t    = out_xhat + (size_t)B * 10; // [B][10], second in tuple
    float* ws       = (float*)d_ws;

    kitsune_prep<<<1, 256, 0, stream>>>(
        tail_enc_w, tail_enc_b, tail_dec_w, tail_dec_b, tail_nmin, tail_nmax,
        head_enc_w, head_enc_b, head_dec_w, head_dec_b, head_nmin, head_nmax, ws);

    const int gridA = (B + 63) / 64;             // 64 rows per block, 5 waves
    kitsune_tail<<<gridA, 320, 0, stream>>>(x, ws, out_t, B);

    const int gridB = (B + 255) / 256;           // 1 row per thread
    kitsune_head<<<gridB, 256, 0, stream>>>(out_t, ws, out_xhat, B);
}

// Round 11
// 68.584 us; speedup vs baseline: 1.6266x; 1.0508x over previous
//
#include <hip/hip_runtime.h>

#define KEPS  1e-16f
#define LOG2E 1.44269504088896340736f

typedef float v2f __attribute__((ext_vector_type(2)));

// ---- d_ws float layout (2178 floats) ----
// [0..99]      tsc : 1/(nmax-nmin+eps)              [c][f]
// [100..199]   tbi : -nmin*tsc                      [c][f]
// [200..999]   tew : tail_enc_w * -log2e            [c][i][f]
// [1000..1079] teb : tail_enc_b * -log2e            [c][i]
// [1080..1879] tdw : tail_dec_w * -log2e            [c][f][i]
// [1880..1979] tdb : tail_dec_b * -log2e            [c][f]
// [1980..1989] hsc : head scale                     [c]
// [1990..1999] hbi : -hnmin*hsc                     [c]
// [2000..2079] hewS: head_enc_w * -log2e            [i][c]
// [2080..2087] hebS: head_enc_b * -log2e            [i]
// [2088..2167] hdwS: head_dec_w * -log2e            [c][i]
// [2168..2177] hdbS: head_dec_b * -log2e            [c]

__global__ void kitsune_prep(
    const float* __restrict__ tew, const float* __restrict__ teb,
    const float* __restrict__ tdw, const float* __restrict__ tdb,
    const float* __restrict__ tnmin, const float* __restrict__ tnmax,
    const float* __restrict__ hew, const float* __restrict__ heb,
    const float* __restrict__ hdw, const float* __restrict__ hdb,
    const float* __restrict__ hnmin, const float* __restrict__ hnmax,
    float* __restrict__ ws)
{
    const int i = threadIdx.x;  // one block of 256
    for (int k = i; k < 100; k += 256) {
        float s = 1.0f / (tnmax[k] - tnmin[k] + KEPS);
        ws[k]        = s;
        ws[100 + k]  = -tnmin[k] * s;
        ws[1880 + k] = tdb[k] * -LOG2E;
    }
    for (int k = i; k < 800; k += 256) {
        ws[200 + k]  = tew[k] * -LOG2E;
        ws[1080 + k] = tdw[k] * -LOG2E;
    }
    for (int k = i; k < 80; k += 256) {
        ws[1000 + k] = teb[k] * -LOG2E;
        ws[2000 + k] = hew[k] * -LOG2E;   // [i][c]
        ws[2088 + k] = hdw[k] * -LOG2E;   // [c][i]
    }
    if (i < 10) {
        float s = 1.0f / (hnmax[i] - hnmin[i] + KEPS);
        ws[1980 + i] = s;
        ws[1990 + i] = -hnmin[i] * s;
        ws[2168 + i] = hdb[i] * -LOG2E;
    }
    if (i < 8) ws[2080 + i] = heb[i] * -LOG2E;
}

// sigmoid with -log2e pre-folded into the matmul: sig2(a) = 1/(1+2^a)
__device__ __forceinline__ float sig2(float a) {
    return __builtin_amdgcn_rcpf(1.0f + __builtin_amdgcn_exp2f(a));
}

// Block = 320 thr = 5 waves = 64 rows, TWO barriers total.
// Phase 2: wave w computes clusters w and w+5 (packed v2f math), writes t to
// LDS + straight to out_t. Phase 3: wave 0 alone runs the head for all 64
// rows from LDS (other waves exit; 6 blocks/CU hide the imbalance).
__global__ __launch_bounds__(320) void kitsune_fused(
    const float* __restrict__ x,    // [B][100]
    const float* __restrict__ ws,
    float* __restrict__ out_xhat,   // [B][10]
    float* __restrict__ out_t,      // [B][10]
    int B)
{
    __shared__ float xs[64 * 102];  // input tile, row stride 102
    __shared__ float ts[64 * 11];   // t values (stride 11)

    const int tid  = threadIdx.x;
    const int base = (int)blockIdx.x * 64;
    const int rows = min(64, B - base);
    const int n25  = rows * 25;

    // ---- phase 1: stage 64 rows, fully coalesced float4 loads ----
    {
        const float4* gx = reinterpret_cast<const float4*>(x) + (size_t)base * 25;
        #pragma unroll
        for (int n = 0; n < 5; ++n) {
            int idx = tid + n * 320;          // float4 index in [0, 1600)
            if (idx < n25) {
                float4 v = gx[idx];
                int row = idx / 25;
                int q   = idx - row * 25;
                float* d = xs + row * 102 + q * 4;
                *reinterpret_cast<float2*>(d)     = make_float2(v.x, v.y);
                *reinterpret_cast<float2*>(d + 2) = make_float2(v.z, v.w);
            }
        }
    }
    __syncthreads();

    // ---- phase 2: tail AEs; lane = row, wave w = clusters w, w+5 ----
    const int r = tid & 63;

    #pragma unroll
    for (int k = 0; k < 2; ++k) {
        const int c = __builtin_amdgcn_readfirstlane((tid >> 6) + 5 * k); // uniform

        v2f xp[5];
        #pragma unroll
        for (int j = 0; j < 5; ++j)
            xp[j] = *reinterpret_cast<const v2f*>(xs + r * 102 + c * 10 + 2 * j);

        const v2f* sc2 = reinterpret_cast<const v2f*>(ws + c * 10);
        const v2f* bi2 = reinterpret_cast<const v2f*>(ws + 100 + c * 10);
        #pragma unroll
        for (int j = 0; j < 5; ++j)
            xp[j] = __builtin_elementwise_fma(xp[j], sc2[j], bi2[j]);

        // encoder: 5 pk_fma per hidden unit
        v2f hv[4];
        #pragma unroll
        for (int i = 0; i < 8; ++i) {
            const v2f* w2 = reinterpret_cast<const v2f*>(ws + 200 + (c * 8 + i) * 10);
            v2f a2 = w2[0] * xp[0];
            #pragma unroll
            for (int j = 1; j < 5; ++j)
                a2 = __builtin_elementwise_fma(w2[j], xp[j], a2);
            hv[i >> 1][i & 1] = sig2(ws[1000 + c * 8 + i] + a2.x + a2.y);
        }

        // decoder + RMSE: 4 pk_fma per output feature
        v2f ss2 = {0.0f, 0.0f};
        float dprev = 0.0f;
        #pragma unroll
        for (int f = 0; f < 10; ++f) {
            const v2f* w2 = reinterpret_cast<const v2f*>(ws + 1080 + (c * 10 + f) * 8);
            v2f a2 = w2[0] * hv[0];
            #pragma unroll
            for (int i = 1; i < 4; ++i)
                a2 = __builtin_elementwise_fma(w2[i], hv[i], a2);
            float rec = sig2(ws[1880 + c * 10 + f] + a2.x + a2.y);
            float d   = rec - xp[f >> 1][f & 1];
            if (f & 1) {
                v2f d2 = {dprev, d};
                ss2 = __builtin_elementwise_fma(d2, d2, ss2);
            } else {
                dprev = d;
            }
        }
        float l    = __builtin_amdgcn_sqrtf((ss2.x + ss2.y) * 0.1f);
        float tail = (l == 0.0f) ? 0.01f : l;
        float tv   = fmaf(tail, ws[1980 + c], ws[1990 + c]);

        ts[r * 11 + c] = tv;
        if (r < rows)
            out_t[(size_t)(base + r) * 10 + c] = tv;   // block covers full lines
    }
    __syncthreads();

    // ---- phase 3: head; wave 0 only, lane = row ----
    if (tid < 64 && tid < rows) {
        const float* tr = ts + tid * 11;
        v2f tp[5];
        #pragma unroll
        for (int j = 0; j < 5; ++j)
            tp[j] = v2f{tr[2 * j], tr[2 * j + 1]};

        v2f hv[4];
        #pragma unroll
        for (int i = 0; i < 8; ++i) {
            const v2f* w2 = reinterpret_cast<const v2f*>(ws + 2000 + i * 10);
            v2f a2 = w2[0] * tp[0];
            #pragma unroll
            for (int j = 1; j < 5; ++j)
                a2 = __builtin_elementwise_fma(w2[j], tp[j], a2);
            hv[i >> 1][i & 1] = sig2(ws[2080 + i] + a2.x + a2.y);
        }

        float xh[10];
        #pragma unroll
        for (int c = 0; c < 10; ++c) {
            const v2f* w2 = reinterpret_cast<const v2f*>(ws + 2088 + c * 8);
            v2f a2 = w2[0] * hv[0];
            #pragma unroll
            for (int i = 1; i < 4; ++i)
                a2 = __builtin_elementwise_fma(w2[i], hv[i], a2);
            xh[c] = sig2(ws[2168 + c] + a2.x + a2.y);
        }

        float* po = out_xhat + (size_t)(base + tid) * 10;
        #pragma unroll
        for (int j = 0; j < 5; ++j)
            *reinterpret_cast<float2*>(po + 2 * j) = make_float2(xh[2 * j], xh[2 * j + 1]);
    }
}

extern "C" void kernel_launch(void* const* d_in, const int* in_sizes, int n_in,
                              void* d_out, int out_size, void* d_ws, size_t ws_size,
                              hipStream_t stream) {
    const float* x          = (const float*)d_in[0];
    const float* tail_enc_w = (const float*)d_in[1];
    const float* tail_enc_b = (const float*)d_in[2];
    const float* tail_dec_w = (const float*)d_in[3];
    const float* tail_dec_b = (const float*)d_in[4];
    const float* tail_nmin  = (const float*)d_in[5];
    const float* tail_nmax  = (const float*)d_in[6];
    const float* head_enc_w = (const float*)d_in[7];
    const float* head_enc_b = (const float*)d_in[8];
    const float* head_dec_w = (const float*)d_in[9];
    const float* head_dec_b = (const float*)d_in[10];
    const float* head_nmin  = (const float*)d_in[11];
    const float* head_nmax  = (const float*)d_in[12];

    const int B = in_sizes[0] / 100;

    float* out_xhat = (float*)d_out;             // [B][10], first in tuple
    float* out_t    = out_xhat + (size_t)B * 10; // [B][10], second in tuple
    float* ws       = (float*)d_ws;

    kitsune_prep<<<1, 256, 0, stream>>>(
        tail_enc_w, tail_enc_b, tail_dec_w, tail_dec_b, tail_nmin, tail_nmax,
        head_enc_w, head_enc_b, head_dec_w, head_dec_b, head_nmin, head_nmax, ws);

    const int grid = (B + 63) / 64;              // 64 rows per block, 5 waves
    kitsune_fused<<<grid, 320, 0, stream>>>(x, ws, out_xhat, out_t, B);
}

// Round 12
// 68.318 us; speedup vs baseline: 1.6329x; 1.0039x over previous
//
#include <hip/hip_runtime.h>

#define KEPS  1e-16f
#define LOG2E 1.44269504088896340736f

typedef float v2f __attribute__((ext_vector_type(2)));

// ---- d_ws float layout (2178 floats) ----
// [0..99]      tsc : 1/(nmax-nmin+eps)              [c][f]
// [100..199]   tbi : -nmin*tsc                      [c][f]
// [200..999]   tew : tail_enc_w * -log2e            [c][i][f]
// [1000..1079] teb : tail_enc_b * -log2e            [c][i]
// [1080..1879] tdw : tail_dec_w * -log2e            [c][f][i]
// [1880..1979] tdb : tail_dec_b * -log2e            [c][f]
// [1980..1989] hsc : head scale                     [c]
// [1990..1999] hbi : -hnmin*hsc                     [c]
// [2000..2079] hewS: head_enc_w * -log2e            [i][c]
// [2080..2087] hebS: head_enc_b * -log2e            [i]
// [2088..2167] hdwS: head_dec_w * -log2e            [c][i]
// [2168..2177] hdbS: head_dec_b * -log2e            [c]

__global__ void kitsune_prep(
    const float* __restrict__ tew, const float* __restrict__ teb,
    const float* __restrict__ tdw, const float* __restrict__ tdb,
    const float* __restrict__ tnmin, const float* __restrict__ tnmax,
    const float* __restrict__ hew, const float* __restrict__ heb,
    const float* __restrict__ hdw, const float* __restrict__ hdb,
    const float* __restrict__ hnmin, const float* __restrict__ hnmax,
    float* __restrict__ ws)
{
    const int i = threadIdx.x;  // one block of 256
    for (int k = i; k < 100; k += 256) {
        float s = 1.0f / (tnmax[k] - tnmin[k] + KEPS);
        ws[k]        = s;
        ws[100 + k]  = -tnmin[k] * s;
        ws[1880 + k] = tdb[k] * -LOG2E;
    }
    for (int k = i; k < 800; k += 256) {
        ws[200 + k]  = tew[k] * -LOG2E;
        ws[1080 + k] = tdw[k] * -LOG2E;
    }
    for (int k = i; k < 80; k += 256) {
        ws[1000 + k] = teb[k] * -LOG2E;
        ws[2000 + k] = hew[k] * -LOG2E;   // [i][c]
        ws[2088 + k] = hdw[k] * -LOG2E;   // [c][i]
    }
    if (i < 10) {
        float s = 1.0f / (hnmax[i] - hnmin[i] + KEPS);
        ws[1980 + i] = s;
        ws[1990 + i] = -hnmin[i] * s;
        ws[2168 + i] = hdb[i] * -LOG2E;
    }
    if (i < 8) ws[2080 + i] = heb[i] * -LOG2E;
}

// sigmoid with -log2e pre-folded into the matmul: sig2(a) = 1/(1+2^a)
__device__ __forceinline__ float sig2(float a) {
    return __builtin_amdgcn_rcpf(1.0f + __builtin_amdgcn_exp2f(a));
}

// commit 5 prefetched float4s into the xs tile (stride 102)
__device__ __forceinline__ void commit_tile(float* xs, const float4* p,
                                            int tid, int ncap) {
    #pragma unroll
    for (int n = 0; n < 5; ++n) {
        int idx = tid + n * 320;
        if (idx < ncap) {
            int row = idx / 25;
            int q   = idx - row * 25;
            float* d = xs + row * 102 + q * 4;
            *reinterpret_cast<float2*>(d)     = make_float2(p[n].x, p[n].y);
            *reinterpret_cast<float2*>(d + 2) = make_float2(p[n].z, p[n].w);
        }
    }
}

// tail AEs for one 64-row tile; lane = row, wave w = clusters w, w+5.
// Writes t to ts[] and scatters it to out_t.
__device__ __forceinline__ void tail_compute(const float* xs, float* ts,
                                             const float* __restrict__ ws,
                                             float* __restrict__ out_t,
                                             int tid, int base, int rows) {
    const int r = tid & 63;
    #pragma unroll
    for (int k = 0; k < 2; ++k) {
        const int c = __builtin_amdgcn_readfirstlane((tid >> 6) + 5 * k);

        v2f xp[5];
        #pragma unroll
        for (int j = 0; j < 5; ++j)
            xp[j] = *reinterpret_cast<const v2f*>(xs + r * 102 + c * 10 + 2 * j);

        const v2f* sc2 = reinterpret_cast<const v2f*>(ws + c * 10);
        const v2f* bi2 = reinterpret_cast<const v2f*>(ws + 100 + c * 10);
        #pragma unroll
        for (int j = 0; j < 5; ++j)
            xp[j] = __builtin_elementwise_fma(xp[j], sc2[j], bi2[j]);

        v2f hv[4];
        #pragma unroll
        for (int i = 0; i < 8; ++i) {
            const v2f* w2 = reinterpret_cast<const v2f*>(ws + 200 + (c * 8 + i) * 10);
            v2f a2 = w2[0] * xp[0];
            #pragma unroll
            for (int j = 1; j < 5; ++j)
                a2 = __builtin_elementwise_fma(w2[j], xp[j], a2);
            hv[i >> 1][i & 1] = sig2(ws[1000 + c * 8 + i] + a2.x + a2.y);
        }

        v2f ss2 = {0.0f, 0.0f};
        float dprev = 0.0f;
        #pragma unroll
        for (int f = 0; f < 10; ++f) {
            const v2f* w2 = reinterpret_cast<const v2f*>(ws + 1080 + (c * 10 + f) * 8);
            v2f a2 = w2[0] * hv[0];
            #pragma unroll
            for (int i = 1; i < 4; ++i)
                a2 = __builtin_elementwise_fma(w2[i], hv[i], a2);
            float rec = sig2(ws[1880 + c * 10 + f] + a2.x + a2.y);
            float d   = rec - xp[f >> 1][f & 1];
            if (f & 1) {
                v2f d2 = {dprev, d};
                ss2 = __builtin_elementwise_fma(d2, d2, ss2);
            } else {
                dprev = d;
            }
        }
        float l    = __builtin_amdgcn_sqrtf((ss2.x + ss2.y) * 0.1f);
        float tail = (l == 0.0f) ? 0.01f : l;
        float tv   = fmaf(tail, ws[1980 + c], ws[1990 + c]);

        ts[r * 11 + c] = tv;
        if (r < rows)
            out_t[(size_t)(base + r) * 10 + c] = tv;
    }
}

// head for one tile; wave 0 only (tid<64), lane = row
__device__ __forceinline__ void head_compute(const float* ts,
                                             const float* __restrict__ ws,
                                             float* __restrict__ out_xhat,
                                             int tid, int base, int rows) {
    if (tid < 64 && tid < rows) {
        const float* tr = ts + tid * 11;
        v2f tp[5];
        #pragma unroll
        for (int j = 0; j < 5; ++j)
            tp[j] = v2f{tr[2 * j], tr[2 * j + 1]};

        v2f hv[4];
        #pragma unroll
        for (int i = 0; i < 8; ++i) {
            const v2f* w2 = reinterpret_cast<const v2f*>(ws + 2000 + i * 10);
            v2f a2 = w2[0] * tp[0];
            #pragma unroll
            for (int j = 1; j < 5; ++j)
                a2 = __builtin_elementwise_fma(w2[j], tp[j], a2);
            hv[i >> 1][i & 1] = sig2(ws[2080 + i] + a2.x + a2.y);
        }

        float xh[10];
        #pragma unroll
        for (int c = 0; c < 10; ++c) {
            const v2f* w2 = reinterpret_cast<const v2f*>(ws + 2088 + c * 8);
            v2f a2 = w2[0] * hv[0];
            #pragma unroll
            for (int i = 1; i < 4; ++i)
                a2 = __builtin_elementwise_fma(w2[i], hv[i], a2);
            xh[c] = sig2(ws[2168 + c] + a2.x + a2.y);
        }

        float* po = out_xhat + (size_t)(base + tid) * 10;
        #pragma unroll
        for (int j = 0; j < 5; ++j)
            *reinterpret_cast<float2*>(po + 2 * j) = make_float2(xh[2 * j], xh[2 * j + 1]);
    }
}

// Block = 320 thr = 5 waves; processes TWO consecutive 64-row tiles,
// software-pipelined: tile1's global loads are issued before tile0's
// compute, so stage latency is exposed only once per kernel.
__global__ __launch_bounds__(320) void kitsune_fused(
    const float* __restrict__ x,    // [B][100]
    const float* __restrict__ ws,
    float* __restrict__ out_xhat,   // [B][10]
    float* __restrict__ out_t,      // [B][10]
    int B)
{
    __shared__ float xs[64 * 102];
    __shared__ float ts[64 * 11];

    const int tid   = threadIdx.x;
    const int base0 = (int)blockIdx.x * 128;
    if (base0 >= B) return;
    const int base1 = base0 + 64;
    const int rows0 = min(64, B - base0);
    const int n0    = rows0 * 25;
    const int rows1 = (base1 < B) ? min(64, B - base1) : 0;
    const int n1    = rows1 * 25;

    const float4* gx = reinterpret_cast<const float4*>(x);

    // ---- prefetch + commit tile0 ----
    {
        float4 p[5];
        #pragma unroll
        for (int n = 0; n < 5; ++n) {
            int idx = tid + n * 320;
            if (idx < n0) p[n] = gx[(size_t)base0 * 25 + idx];
        }
        commit_tile(xs, p, tid, n0);
    }

    // ---- issue tile1's loads (fly under tile0's compute) ----
    float4 q[5];
    if (rows1 > 0) {
        #pragma unroll
        for (int n = 0; n < 5; ++n) {
            int idx = tid + n * 320;
            if (idx < n1) q[n] = gx[(size_t)base1 * 25 + idx];
        }
    }
    __syncthreads();

    // ---- tile0: tail ----
    tail_compute(xs, ts, ws, out_t, tid, base0, rows0);
    __syncthreads();

    // ---- commit tile1 (all waves) + head tile0 (wave 0) ----
    if (rows1 > 0) commit_tile(xs, q, tid, n1);
    head_compute(ts, ws, out_xhat, tid, base0, rows0);
    __syncthreads();

    if (rows1 == 0) return;

    // ---- tile1: tail + head ----
    tail_compute(xs, ts, ws, out_t, tid, base1, rows1);
    __syncthreads();
    head_compute(ts, ws, out_xhat, tid, base1, rows1);
}

extern "C" void kernel_launch(void* const* d_in, const int* in_sizes, int n_in,
                              void* d_out, int out_size, void* d_ws, size_t ws_size,
                              hipStream_t stream) {
    const float* x          = (const float*)d_in[0];
    const float* tail_enc_w = (const float*)d_in[1];
    const float* tail_enc_b = (const float*)d_in[2];
    const float* tail_dec_w = (const float*)d_in[3];
    const float* tail_dec_b = (const float*)d_in[4];
    const float* tail_nmin  = (const float*)d_in[5];
    const float* tail_nmax  = (const float*)d_in[6];
    const float* head_enc_w = (const float*)d_in[7];
    const float* head_enc_b = (const float*)d_in[8];
    const float* head_dec_w = (const float*)d_in[9];
    const float* head_dec_b = (const float*)d_in[10];
    const float* head_nmin  = (const float*)d_in[11];
    const float* head_nmax  = (const float*)d_in[12];

    const int B = in_sizes[0] / 100;

    float* out_xhat = (float*)d_out;             // [B][10], first in tuple
    float* out_t    = out_xhat + (size_t)B * 10; // [B][10], second in tuple
    float* ws       = (float*)d_ws;

    kitsune_prep<<<1, 256, 0, stream>>>(
        tail_enc_w, tail_enc_b, tail_dec_w, tail_dec_b, tail_nmin, tail_nmax,
        head_enc_w, head_enc_b, head_dec_w, head_dec_b, head_nmin, head_nmax, ws);

    const int grid = (B + 127) / 128;            // 2 tiles (128 rows) per block
    kitsune_fused<<<grid, 320, 0, stream>>>(x, ws, out_xhat, out_t, B);
}